// Round 8
// baseline (5846.103 us; speedup 1.0000x reference)
//
#include <hip/hip_runtime.h>

typedef float f32x4 __attribute__((ext_vector_type(4)));
typedef int i32x4 __attribute__((ext_vector_type(4)));

#define HDIM 2048
#define BATCH 256
#define TSTEPS 300
#define NBLK 256
#define NTHR 256

// ws layout (bytes)
#define W8_OFF  0u          // 4 MB  : wrec^T int8-hi, MFMA B-frag order [bi][ct][kb][lane][16]
#define W2_OFF  4194304u    // 1 MB  : wrec^T 2-bit lo crumbs, dword per [bi][ct][kb][lane]
#define RHI_OFF 5242880u    // 1 MB  : r hi int8, 2x[256][2048]
#define RLO_OFF 6291456u    // 1 MB  : r lo int8, 2x[256][2048]
#define WI_OFF  7340032u    // 32 KB : wi_full f32 [4][2048]
#define WO_OFF  7372800u    // 16 KB : wo_full f32 [2][2048]
#define SC_OFF  7389184u    // 8 KB  : per-col scale s[2048]
#define BAR_OFF 7397376u    // 4 KB  : barrier area

// bar u32 indices
#define BF_FLAG(x,i) ((x) * 64 + (i))   // words [0,512): per-XCD 64-slot flag arrays
#define B_GCNT0 544                     // init barrier counter
#define B_XTOT(x) (576 + (x))           // per-XCD registration counters

#define AGENT __HIP_MEMORY_SCOPE_AGENT

__device__ inline float tanh_fast(float x) {
  float e = __expf(2.0f * x);
  return 1.0f - 2.0f / (e + 1.0f);
}

// s[j] = max_k |wrec[j][k]| / 127,  wrec[j][k] = rec_noise[j][k] + m[j,:].n[k,:]
__global__ void prep_scale(const float* __restrict__ rec_noise,
                           const float* __restrict__ m, const float* __restrict__ n,
                           float* __restrict__ s) {
  int w = threadIdx.x >> 6, l = threadIdx.x & 63;
  int j = blockIdx.x * 4 + w;
  float m0 = m[j * 2], m1 = m[j * 2 + 1];
  float vmax = 0.f;
  for (int it = 0; it < HDIM / 64; ++it) {
    int k = it * 64 + l;
    float v = rec_noise[(size_t)j * HDIM + k] + m0 * n[k * 2] + m1 * n[k * 2 + 1];
    vmax = fmaxf(vmax, fabsf(v));
  }
#pragma unroll
  for (int d = 1; d < 64; d <<= 1) vmax = fmaxf(vmax, __shfl_xor(vmax, d, 64));
  if (l == 0) s[j] = fmaxf(vmax, 1e-20f) / 127.f;
}

// int8-hi bytes (B-frag order, same mapping as verified round-7 prep) + 2-bit lo crumbs.
// gid = bi<<13 | ct<<11 | kb<<6 | lane ; thread handles i=0..15 (one W2 dword).
__global__ void prep_w8w2(const float* __restrict__ rec_noise,
                          const float* __restrict__ m, const float* __restrict__ n,
                          const float* __restrict__ s,
                          char* __restrict__ W8, unsigned* __restrict__ W2) {
  int gid = blockIdx.x * 256 + threadIdx.x;   // [0, 262144)
  int lane = gid & 63;
  int kb = (gid >> 6) & 31;
  int ct = (gid >> 11) & 3;
  int bi = gid >> 13;                          // [0,32)
  int col = bi * 64 + ct * 16 + (lane & 15);
  int kbase = kb * 64 + (lane >> 4) * 16;
  float sc = s[col];
  float m0 = m[col * 2], m1 = m[col * 2 + 1];
  unsigned crumbs = 0u;
  size_t b8 = (size_t)((lane << 4) | (kb << 10) | (ct << 15)) + ((size_t)bi << 17);
#pragma unroll 4
  for (int i = 0; i < 16; ++i) {
    int k = kbase + i;
    float v = (rec_noise[(size_t)col * HDIM + k] + m0 * n[k * 2] + m1 * n[k * 2 + 1]) / sc;
    int q8 = __float2int_rn(v);
    q8 = max(-127, min(127, q8));
    float f = v - (float)q8;                   // [-0.5, 0.5]
    int q2 = (int)floorf(4.f * f);
    q2 = max(-2, min(1, q2));                  // lo value = (2*q2+1)/8 in s units
    W8[b8 + i] = (char)q8;
    crumbs |= (unsigned)(q2 + 2) << (2 * i);
  }
  W2[gid] = crumbs;
}

// wi_full, wo_full, r0 (hi/lo int8 pair)
__global__ void prep_small(const float* __restrict__ wi, const float* __restrict__ si,
                           const float* __restrict__ wo, const float* __restrict__ so,
                           const float* __restrict__ h0,
                           float* __restrict__ wi_full, float* __restrict__ wo_full,
                           char* __restrict__ rhi0, char* __restrict__ rlo0) {
  int idx = blockIdx.x * 256 + threadIdx.x;
  if (idx < BATCH * HDIM) {
    int j = idx & (HDIM - 1);
    int Q = __float2int_rn(16256.f * tanh_fast(h0[j]));
    int ah = (Q + 64) >> 7;
    int al = Q - (ah << 7);
    rhi0[idx] = (char)ah;
    rlo0[idx] = (char)al;
  }
  if (idx < 4 * HDIM) wi_full[idx] = wi[idx] * si[idx >> 11];
  if (idx < 2 * HDIM) {
    int o = idx >> 11, j = idx & (HDIM - 1);
    wo_full[idx] = wo[j * 2 + o] * so[o];
  }
}

// XCD-local persistent RNN. W-hi int8 in LDS, W-lo 2-bit in VGPRs, r as int8 hi/lo pair.
// rec = s * (128*(ahi.q8) + (alo.q8) + 16*(ahi.wlo')) / 16256, wlo' = 2*q2+1.
// Sync: flag-array barrier (plain AGENT store arrive, lane-parallel AGENT-load poll,
// single L1 buffer_inv) -- zero RMW, zero leader relay, zero L2 maintenance.
__global__ __launch_bounds__(NTHR, 1) void rnn_run(
    const float* __restrict__ inp, const float* __restrict__ noise,
    const char* __restrict__ W8, const unsigned* __restrict__ W2,
    char* __restrict__ rhi, char* __restrict__ rlo,
    const float* __restrict__ wi_full, const float* __restrict__ wo_full,
    const float* __restrict__ scales, const float* __restrict__ h0,
    float* __restrict__ out, unsigned* __restrict__ bar) {
  extern __shared__ char Wlds[];  // 128 KB: W-hi slice (frag order)

  const int tid = threadIdx.x;
  const int l = tid & 63, w = tid >> 6;
  const int lr = l & 15, hi = l >> 4;

  // ---- registration (round-6/7-proven) ----
  if (tid == 0) {
    unsigned xcc_ = (unsigned)__builtin_amdgcn_s_getreg((31u << 11) | 20u) & 7u;  // HW_REG_XCC_ID
    unsigned idx_ = __hip_atomic_fetch_add(bar + B_XTOT(xcc_), 1u, __ATOMIC_RELAXED, AGENT);
    __hip_atomic_fetch_add(bar + B_GCNT0, 1u, __ATOMIC_RELEASE, AGENT);
    while (__hip_atomic_load(bar + B_GCNT0, __ATOMIC_RELAXED, AGENT) < (unsigned)NBLK)
      __builtin_amdgcn_s_sleep(1);
    __builtin_amdgcn_fence(__ATOMIC_ACQUIRE, "agent");
    unsigned nm_ = __hip_atomic_load(bar + B_XTOT(xcc_), __ATOMIC_RELAXED, AGENT);
    ((unsigned*)Wlds)[0] = xcc_;
    ((unsigned*)Wlds)[1] = idx_;
    ((unsigned*)Wlds)[2] = nm_;
  }
  __syncthreads();
  const int xcc = (int)((unsigned*)Wlds)[0];
  const int bi = (int)((unsigned*)Wlds)[1];
  const unsigned n_mine = ((unsigned*)Wlds)[2];
  __syncthreads();

  const int rbase = xcc * 32;                  // my XCD's 32 batch rows
  const int colw = bi * 64 + w * 16 + lr;      // this lane's output column

  // one-time: W-hi slice -> LDS
  {
    const f32x4* src = (const f32x4*)(W8 + (size_t)bi * 131072);
    f32x4* dst = (f32x4*)Wlds;
    for (int u = tid; u < 8192; u += NTHR) dst[u] = src[u];
  }
  // one-time: W-lo crumbs -> 32 VGPRs
  unsigned w2r[32];
  {
    const unsigned* w2g = W2 + ((size_t)bi * 4 + w) * 32 * 64 + l;
#pragma unroll
    for (int kb = 0; kb < 32; ++kb) w2r[kb] = w2g[kb * 64];
  }

  const float swq = scales[colw] * (1.f / 16256.f);
  float wic[4];
#pragma unroll
  for (int i = 0; i < 4; ++i) wic[i] = wi_full[i * HDIM + colw];
  const float wo0 = wo_full[colw], wo1 = wo_full[HDIM + colw];

  float h[2][4];
  {
    float a = h0[colw];
#pragma unroll
    for (int rt = 0; rt < 2; ++rt)
#pragma unroll
      for (int q = 0; q < 4; ++q) h[rt][q] = a;
  }
  __syncthreads();

  // prefetch t=0 noise + input-dot
  float nz[2][4], xd[2][4];
#pragma unroll
  for (int rt = 0; rt < 2; ++rt)
#pragma unroll
    for (int q = 0; q < 4; ++q) {
      const int brow = rbase + rt * 16 + hi * 4 + q;
      nz[rt][q] = noise[((size_t)brow * TSTEPS + 0) * HDIM + colw];
      float4 x = *(const float4*)(inp + ((size_t)brow * TSTEPS + 0) * 4);
      xd[rt][q] = x.x * wic[0] + x.y * wic[1] + x.z * wic[2] + x.w * wic[3];
    }

  const char* ldsB = Wlds + w * 32768 + l * 16;   // + kb*1024

  for (int t = 0; t < TSTEPS; ++t) {
    const char* rrh = rhi + (size_t)(t & 1) * (BATCH * HDIM);
    const char* rrl = rlo + (size_t)(t & 1) * (BATCH * HDIM);
    char* rwh = rhi + (size_t)((t + 1) & 1) * (BATCH * HDIM);
    char* rwl = rlo + (size_t)((t + 1) & 1) * (BATCH * HDIM);

    // ---- GEMM: 3 int8 passes over this block's 64 cols x 32 rows x K2048 ----
    const i32x4* ah0 = (const i32x4*)(rrh + (size_t)(rbase + lr) * HDIM + hi * 16);
    const i32x4* ah1 = (const i32x4*)(rrh + (size_t)(rbase + 16 + lr) * HDIM + hi * 16);
    const i32x4* al0 = (const i32x4*)(rrl + (size_t)(rbase + lr) * HDIM + hi * 16);
    const i32x4* al1 = (const i32x4*)(rrl + (size_t)(rbase + 16 + lr) * HDIM + hi * 16);
    i32x4 rh0[8], rh1[8], rl0[8], rl1[8];
#pragma unroll
    for (int i = 0; i < 8; ++i) {
      rh0[i] = ah0[i * 4]; rh1[i] = ah1[i * 4];
      rl0[i] = al0[i * 4]; rl1[i] = al1[i * 4];
    }
    i32x4 accA0 = {0,0,0,0}, accA1 = {0,0,0,0};   // ahi . q8
    i32x4 accB0 = {0,0,0,0}, accB1 = {0,0,0,0};   // alo . q8
    i32x4 accC0 = {0,0,0,0}, accC1 = {0,0,0,0};   // ahi . wlo'
#pragma unroll
    for (int kb = 0; kb < 32; ++kb) {
      i32x4 bW = *(const i32x4*)(ldsB + kb * 1024);
      // unpack 16 crumbs -> 16 int8 in {-3,-1,1,3} via byte-LUT v_perm
      unsigned v = w2r[kb];
      i32x4 bL;
#pragma unroll
      for (int g = 0; g < 4; ++g) {
        unsigned vg = (v >> (8 * g)) & 0xFFu;
        unsigned tt = (vg | (vg << 12)) & 0x000F000Fu;
        tt = (tt | (tt << 6)) & 0x03030303u;
        bL[g] = (int)__builtin_amdgcn_perm(0u, 0x0301FFFDu, tt);
      }
      i32x4 a0 = rh0[kb & 7], a1 = rh1[kb & 7];
      accA0 = __builtin_amdgcn_mfma_i32_16x16x64_i8(a0, bW, accA0, 0, 0, 0);
      accA1 = __builtin_amdgcn_mfma_i32_16x16x64_i8(a1, bW, accA1, 0, 0, 0);
      accC0 = __builtin_amdgcn_mfma_i32_16x16x64_i8(a0, bL, accC0, 0, 0, 0);
      accC1 = __builtin_amdgcn_mfma_i32_16x16x64_i8(a1, bL, accC1, 0, 0, 0);
      accB0 = __builtin_amdgcn_mfma_i32_16x16x64_i8(rl0[kb & 7], bW, accB0, 0, 0, 0);
      accB1 = __builtin_amdgcn_mfma_i32_16x16x64_i8(rl1[kb & 7], bW, accB1, 0, 0, 0);
      if (kb < 24) {
        rh0[kb & 7] = ah0[(kb + 8) * 4]; rh1[kb & 7] = ah1[(kb + 8) * 4];
        rl0[kb & 7] = al0[(kb + 8) * 4]; rl1[kb & 7] = al1[(kb + 8) * 4];
      }
    }

    // ---- h update + write r_{t+1} (hi/lo int8, plain stores -> own-XCD L2) ----
    float ro[2][4];
#pragma unroll
    for (int rt = 0; rt < 2; ++rt) {
      i32x4 A = rt ? accA1 : accA0;
      i32x4 B = rt ? accB1 : accB0;
      i32x4 C = rt ? accC1 : accC0;
#pragma unroll
      for (int q = 0; q < 4; ++q) {
        float rec = swq * (128.f * (float)A[q] + (float)B[q] + 16.f * (float)C[q]);
        float hn = 0.8f * h[rt][q] + 0.05f * nz[rt][q] + 0.2f * (rec + xd[rt][q]);
        h[rt][q] = hn;
        float r_ = tanh_fast(hn);
        ro[rt][q] = r_;
        int Q = __float2int_rn(16256.f * r_);
        int ah = (Q + 64) >> 7;
        int al = Q - (ah << 7);
        const int brow = rbase + rt * 16 + hi * 4 + q;
        rwh[(size_t)brow * HDIM + colw] = (char)ah;
        rwl[(size_t)brow * HDIM + colw] = (char)al;
      }
    }

    // ---- arrive: syncthreads drains r stores into local L2; ONE plain flag store ----
    __syncthreads();
    if (t + 1 < TSTEPS && tid == 0)
      __hip_atomic_store(bar + BF_FLAG(xcc, bi), (unsigned)(t + 1), __ATOMIC_RELAXED, AGENT);

    // ---- hidden under barrier: out_t from f32 register r ----
#pragma unroll
    for (int rt = 0; rt < 2; ++rt)
#pragma unroll
      for (int q = 0; q < 4; ++q) {
        float p0 = ro[rt][q] * wo0, p1 = ro[rt][q] * wo1;
        p0 += __shfl_xor(p0, 1, 64); p1 += __shfl_xor(p1, 1, 64);
        p0 += __shfl_xor(p0, 2, 64); p1 += __shfl_xor(p1, 2, 64);
        p0 += __shfl_xor(p0, 4, 64); p1 += __shfl_xor(p1, 4, 64);
        p0 += __shfl_xor(p0, 8, 64); p1 += __shfl_xor(p1, 8, 64);
        if (lr == 0) {
          const int brow = rbase + rt * 16 + hi * 4 + q;
          float* op = out + (size_t)brow * (TSTEPS * 2) + (size_t)t * 2;
          atomicAdd(op, p0);
          atomicAdd(op + 1, p1);
        }
      }

    if (t + 1 < TSTEPS) {
      // ---- hidden under barrier: prefetch t+1 noise + input-dot ----
#pragma unroll
      for (int rt = 0; rt < 2; ++rt)
#pragma unroll
        for (int q = 0; q < 4; ++q) {
          const int brow = rbase + rt * 16 + hi * 4 + q;
          nz[rt][q] = noise[((size_t)brow * TSTEPS + (t + 1)) * HDIM + colw];
          float4 x = *(const float4*)(inp + ((size_t)brow * TSTEPS + (t + 1)) * 4);
          xd[rt][q] = x.x * wic[0] + x.y * wic[1] + x.z * wic[2] + x.w * wic[3];
        }
      // ---- wait: lane-parallel flag poll (no RMW, no leader) ----
      if (w == 0) {
        const unsigned tgt = (unsigned)(t + 1);
        for (;;) {
          unsigned fl = (l < (int)n_mine)
              ? __hip_atomic_load(bar + BF_FLAG(xcc, l), __ATOMIC_RELAXED, AGENT)
              : tgt;
          if (__all(fl >= tgt)) break;
        }
      }
      __syncthreads();
      // per-CU L1 invalidate so A-reads see same-XCD siblings' L2 data
      asm volatile("buffer_inv" ::: "memory");
      asm volatile("s_waitcnt vmcnt(0)" ::: "memory");
      __builtin_amdgcn_sched_barrier(0);
    }
  }
}

extern "C" void kernel_launch(void* const* d_in, const int* in_sizes, int n_in,
                              void* d_out, int out_size, void* d_ws, size_t ws_size,
                              hipStream_t stream) {
  const float* inp = (const float*)d_in[0];
  const float* noise = (const float*)d_in[1];
  const float* wi = (const float*)d_in[2];
  const float* si = (const float*)d_in[3];
  const float* m = (const float*)d_in[4];
  const float* n = (const float*)d_in[5];
  const float* rec_noise = (const float*)d_in[6];
  const float* wo = (const float*)d_in[7];
  const float* so = (const float*)d_in[8];
  const float* h0 = (const float*)d_in[9];

  char* ws = (char*)d_ws;
  char* W8 = ws + W8_OFF;
  unsigned* W2 = (unsigned*)(ws + W2_OFF);
  char* rhi = ws + RHI_OFF;
  char* rlo = ws + RLO_OFF;
  float* wi_full = (float*)(ws + WI_OFF);
  float* wo_full = (float*)(ws + WO_OFF);
  float* sc = (float*)(ws + SC_OFF);
  unsigned* bar = (unsigned*)(ws + BAR_OFF);
  float* outp = (float*)d_out;

  // rebuild proxy params every call (ws poisoned before timing)
  prep_scale<<<512, 256, 0, stream>>>(rec_noise, m, n, sc);
  prep_w8w2<<<1024, 256, 0, stream>>>(rec_noise, m, n, sc, W8, W2);
  prep_small<<<2048, 256, 0, stream>>>(wi, si, wo, so, h0, wi_full, wo_full, rhi, rlo);
  hipMemsetAsync(d_out, 0, (size_t)out_size * sizeof(float), stream);
  hipMemsetAsync(bar, 0, 4096, stream);

  hipFuncSetAttribute((const void*)rnn_run, hipFuncAttributeMaxDynamicSharedMemorySize, 131072);
  const char* W8c = W8;
  const unsigned* W2c = W2;
  const float* scc = sc;
  const float* wic = wi_full;
  const float* woc = wo_full;
  void* kargs[12] = {(void*)&inp, (void*)&noise, (void*)&W8c, (void*)&W2c,
                     (void*)&rhi, (void*)&rlo, (void*)&wic, (void*)&woc,
                     (void*)&scc, (void*)&h0, (void*)&outp, (void*)&bar};
  hipError_t lerr = hipLaunchCooperativeKernel((void*)rnn_run, dim3(NBLK), dim3(NTHR),
                                               kargs, 131072, stream);
  if (lerr != hipSuccess) {
    rnn_run<<<dim3(NBLK), dim3(NTHR), 131072, stream>>>(
        inp, noise, W8, W2, rhi, rlo, wi_full, wo_full, sc, h0, outp, bar);
  }
}